// Round 9
// baseline (261.444 us; speedup 1.0000x reference)
//
#include <hip/hip_runtime.h>
#include <math.h>

// SpinSphericalBlock: separable spin-weighted SHT -> channel mix -> inverse SHT
// -> complex BN (spin0 mean, via Parseval on G) -> magnitude-ReLU gating.
//
// Constants: B=8, RES=64, RES_OUT=32, L=15, SPINS_IN=(0,1), SPINS_OUT=(0,1,2),
// C_IN=64, C_OUT=128, NM=31. Output: out_size=3,145,728 float32 = Re(y),
// (b,t,p,s,d) row-major (established R0-R4).
//
// R9 (post-mortem R8): (1) k_mix had 1 block/CU (6 waves) -> split b 2-ways,
// 512 blocks, 12 waves/CU; LDS layout c[b][iu] kills the 114K staging bank
// conflicts. (2) k_synth_final VGPR_Count=44 < 124 live regs -> compiler
// spilled rotation state to scratch (the 80ms profiled outlier); fix with
// __launch_bounds__(384,1). Same for k_phi_in (512,2).
//
//   K0 k_tables:     Wigner tables (fp64) + zero stats accumulators
//   K1 k_phi_in:     F[bt,m,iu]    = sum_p x[bt,p,iu] e^{-im phi_p}   (rotation)
//   K2 k_theta_in:   coeffs[b,k,iu]= sum_t A_in[i,k,t] F[b,t,m(k),iu]
//   K3 k_mix:        oc[b,k,sd]    = sum_iu coeffs * kernel[l(k),i,s,u,d]
//   K4 k_theta_out:  G[bt,m,sd]    = sum_l A_out[s,k,t] oc[b,k,sd]  + stats
//   K5 k_synth_final: y = BN(sum_m G e^{+im phi'_p}) -> gate -> Re(y) (rotation)

#define PI_D 3.14159265358979323846

// ---------------- workspace layout (bytes) ----------------
#define OFF_A_IN    ((size_t)24320)     // 2*256*64 float    = 131072
#define OFF_A_OUT   ((size_t)155648)    // 3*256*32 float    = 98304
#define OFF_STATS   ((size_t)254208)    // 3*384 float       = 4608
#define OFF_R1      ((size_t)260608)    // F (16.25MB) then oc (6.3MB)
#define OFF_R2      ((size_t)25426688)  // coeffs (2.1MB) then G (24.4MB)

__device__ inline int isqrt_k(int k) {
    int l = (int)sqrtf((float)k + 0.5f);
    while (l * l > k) --l;
    while ((l + 1) * (l + 1) <= k) ++l;
    return l;
}

// d^l_{m,n}(theta), exact factorial-sum formula, double precision.
__device__ double wigner_d_dev(int l, int m, int n, double theta, const double* lf) {
    int an = n < 0 ? -n : n;
    int am = m < 0 ? -m : m;
    if (l < an || l < am) return 0.0;
    double cb = cos(0.5 * theta), sb = sin(0.5 * theta);
    double pref = 0.5 * (lf[l + m] + lf[l - m] + lf[l + n] + lf[l - n]);
    int kmin = max(0, n - m), kmax = min(l + n, l - m);
    if (kmax < kmin) return 0.0;
    double p = pow(cb, (double)(2 * l + n - m - 2 * kmin)) * pow(sb, (double)(m - n + 2 * kmin));
    double r = (sb * sb) / (cb * cb);
    double acc = 0.0;
    for (int k = kmin; k <= kmax; ++k) {
        double lg = pref - (lf[l + n - k] + lf[k] + lf[m - n + k] + lf[l - m - k]);
        double term = exp(lg) * p;
        acc += ((m - n + k) & 1) ? -term : term;
        p *= r;
    }
    return acc;
}

// K0: Wigner tables + zero stats. ranges: A_in 32768 | A_out 24576 | stats 1152
__global__ __launch_bounds__(256) void k_tables(float* __restrict__ A_in,
                                                float* __restrict__ A_out,
                                                float* __restrict__ stats) {
    __shared__ double lf[40];
    if (threadIdx.x == 0) {
        lf[0] = 0.0;
        for (int j = 1; j < 40; ++j) lf[j] = lf[j - 1] + log((double)j);
    }
    __syncthreads();
    int idx = blockIdx.x * 256 + threadIdx.x;
    if (idx < 32768) {
        int t = idx & 63, k = (idx >> 6) & 255, i = idx >> 14;
        int l = isqrt_k(k);
        int m = k - l * l - l;
        int n = -i;
        double theta = ((double)t + 0.5) * PI_D / 64.0;
        double w = sin(theta) * (PI_D / 64.0) * (2.0 * PI_D / 64.0);
        double norm = sqrt((2.0 * l + 1.0) / (4.0 * PI_D));
        double d = wigner_d_dev(l, m, n, theta, lf);
        A_in[idx] = (float)(((m & 1) ? -1.0 : 1.0) * norm * w * d);
        return;
    }
    idx -= 32768;
    if (idx < 24576) {
        int t = idx & 31, k = (idx >> 5) & 255, s = idx >> 13;
        int l = isqrt_k(k);
        int m = k - l * l - l;
        int n = -s;
        double theta = ((double)t + 0.5) * PI_D / 32.0;
        double norm = sqrt((2.0 * l + 1.0) / (4.0 * PI_D));
        double d = wigner_d_dev(l, m, n, theta, lf);
        A_out[idx] = (float)(((m & 1) ? -1.0 : 1.0) * norm * d);
        return;
    }
    idx -= 24576;
    if (idx < 1152) stats[idx] = 0.f;
}

// K1: partial phi-DFT via register rotation. (512,2): VGPR cap 256 -> no spill
// of the 48-reg rotation state.
__global__ __launch_bounds__(512, 2) void k_phi_in(const float* __restrict__ xr,
                                                   const float* __restrict__ xi,
                                                   float2* __restrict__ F) {
    int bt = blockIdx.x;
    int iu = threadIdx.x & 127, mh = threadIdx.x >> 7;
    int mi0 = mh * 8;
    float2 acc[8], w[8], st[8];
#pragma unroll
    for (int j = 0; j < 8; ++j) {
        int m = mi0 + j - 15;
        float sy, sx;
        __sincosf(-(float)m * (float)(PI_D / 32.0), &sy, &sx);
        st[j] = make_float2(sx, sy);
        w[j] = make_float2(1.f, 0.f);
        acc[j] = make_float2(0.f, 0.f);
    }
    const float* xrb = xr + (size_t)bt * 8192 + iu;
    const float* xib = xi + (size_t)bt * 8192 + iu;
    for (int p = 0; p < 64; ++p) {
        float a = xrb[(size_t)p * 128];
        float b = xib[(size_t)p * 128];
#pragma unroll
        for (int j = 0; j < 8; ++j) {
            acc[j].x += a * w[j].x - b * w[j].y;
            acc[j].y += a * w[j].y + b * w[j].x;
            float nx = w[j].x * st[j].x - w[j].y * st[j].y;
            w[j].y = w[j].x * st[j].y + w[j].y * st[j].x;
            w[j].x = nx;
        }
    }
    float2* Fb = F + (size_t)bt * 31 * 128 + iu;
#pragma unroll
    for (int j = 0; j < 8; ++j) {
        int mi = mi0 + j;
        if (mi < 31) Fb[(size_t)mi * 128] = acc[j];
    }
}

// K2: theta contraction. grid (31, 8) = (mi, b), 512 threads (iu, th=t-quarter).
// All 16 l (both parities) per thread; F read ONCE; LDS tree-reduce over th.
__global__ __launch_bounds__(512, 2) void k_theta_in(const float2* __restrict__ F,
                                                     const float* __restrict__ A_in,
                                                     float2* __restrict__ coeffs) {
    __shared__ float A[2][16][64];      // 8 KB, zero-padded below |m|
    __shared__ float2 red[2][16][128];  // 32 KB reduction buffer
    int mi = blockIdx.x, b = blockIdx.y;
    int m = mi - 15;
    int am = m < 0 ? -m : m;
    int tid = threadIdx.x;
    for (int idx = tid; idx < 2048; idx += 512) {
        int i = idx >> 10, j = (idx >> 6) & 15, t = idx & 63;
        float v = 0.f;
        if (j >= am) v = A_in[((size_t)i * 256 + (j * j + j + m)) * 64 + t];
        A[i][j][t] = v;
    }
    __syncthreads();
    int iu = tid & 127, th = tid >> 7, i = iu >> 6;
    float2 acc[16];
#pragma unroll
    for (int j = 0; j < 16; ++j) acc[j] = make_float2(0.f, 0.f);
    const float2* Fb = F + ((size_t)b * 64 * 31 + mi) * 128 + iu;
    for (int tt = 0; tt < 16; ++tt) {
        int t = th * 16 + tt;
        float2 f = Fb[(size_t)t * 31 * 128];
#pragma unroll
        for (int j = 0; j < 16; ++j) {
            float a = A[i][j][t];   // wave-uniform -> broadcast
            acc[j].x += a * f.x;
            acc[j].y += a * f.y;
        }
    }
    if (th >= 2) {
#pragma unroll
        for (int j = 0; j < 16; ++j) red[th - 2][j][iu] = acc[j];
    }
    __syncthreads();
    if (th < 2) {
#pragma unroll
        for (int j = 0; j < 16; ++j) {
            float2 r = red[th][j][iu];
            acc[j].x += r.x;
            acc[j].y += r.y;
        }
    }
    __syncthreads();
    if (th == 1) {
#pragma unroll
        for (int j = 0; j < 16; ++j) red[0][j][iu] = acc[j];
    }
    __syncthreads();
    if (th == 0) {
#pragma unroll
        for (int j = 0; j < 16; ++j) {
            if (j >= am) {
                float2 r = red[0][j][iu];
                coeffs[((size_t)b * 256 + (j * j + j + m)) * 128 + iu] =
                    make_float2(acc[j].x + r.x, acc[j].y + r.y);
            }
        }
    }
}

// K3: channel mix. grid (256 k, 2 b-halves), 384 threads (sd); 4 b per block.
// 512 blocks -> ~2 blocks/CU, 12 waves/CU. LDS c[b][iu]: staging writes are
// lane-consecutive (conflict-free), loop reads uniform (broadcast).
__global__ __launch_bounds__(384) void k_mix(const float2* __restrict__ coeffs,
                                             const float* __restrict__ kr,
                                             const float* __restrict__ ki,
                                             float2* __restrict__ oc) {
    __shared__ float2 c[4][128];  // 4 KB
    int k = blockIdx.x;
    int b0 = blockIdx.y * 4;
    int l = isqrt_k(k);
    int tid = threadIdx.x;
    for (int idx = tid; idx < 512; idx += 384) {
        int bb = idx >> 7, iu = idx & 127;
        c[bb][iu] = coeffs[((size_t)(b0 + bb) * 256 + k) * 128 + iu];
    }
    __syncthreads();
    int sd = tid, s = sd >> 7, d = sd & 127;
    float2 acc[4];
#pragma unroll
    for (int bb = 0; bb < 4; ++bb) acc[bb] = make_float2(0.f, 0.f);
    size_t base = ((size_t)(6 * l + s) * 64) * 128 + d;  // ((2l+i)*3+s), i=0
    for (int i = 0; i < 2; ++i) {
        const float* krp = kr + base + (size_t)i * 3 * 8192;
        const float* kip = ki + base + (size_t)i * 3 * 8192;
#pragma unroll 8
        for (int u = 0; u < 64; ++u) {
            float wr = krp[(size_t)u * 128];
            float wi = kip[(size_t)u * 128];
            int iu = i * 64 + u;
#pragma unroll
            for (int bb = 0; bb < 4; ++bb) {
                float2 cv = c[bb][iu];
                acc[bb].x += cv.x * wr - cv.y * wi;
                acc[bb].y += cv.x * wi + cv.y * wr;
            }
        }
    }
#pragma unroll
    for (int bb = 0; bb < 4; ++bb)
        oc[((size_t)(b0 + bb) * 256 + k) * 384 + sd] = acc[bb];
}

// K4: theta expansion + stats. grid (31, 8), 384 threads.
__global__ __launch_bounds__(384, 2) void k_theta_out(const float2* __restrict__ oc,
                                                      const float* __restrict__ A_out,
                                                      float2* __restrict__ G,
                                                      float* __restrict__ ssr,
                                                      float* __restrict__ ssi,
                                                      float* __restrict__ ssq) {
    __shared__ float Ao[3][16][32];  // 6KB
    int mi = blockIdx.x, b = blockIdx.y;
    int m = mi - 15;
    int am = m < 0 ? -m : m;
    int tid = threadIdx.x;
    for (int idx = tid; idx < 1536; idx += 384) {
        int s = idx >> 9, j = (idx >> 5) & 15, t = idx & 31;
        float v = 0.f;
        if (j >= am) v = A_out[((size_t)s * 256 + (j * j + j + m)) * 32 + t];
        Ao[s][j][t] = v;
    }
    __syncthreads();
    int s = tid >> 7;
    float2 c[16];
#pragma unroll
    for (int j = 0; j < 16; ++j) {
        c[j] = make_float2(0.f, 0.f);
        if (j >= am) c[j] = oc[((size_t)b * 256 + (j * j + j + m)) * 384 + tid];
    }
    float sq = 0.f, sr = 0.f, si = 0.f;
    for (int t = 0; t < 32; ++t) {
        float fr = 0.f, fi = 0.f;
#pragma unroll
        for (int j = 0; j < 16; ++j) {
            float a = Ao[s][j][t];
            fr += a * c[j].x;
            fi += a * c[j].y;
        }
        G[(((size_t)b * 32 + t) * 31 + mi) * 384 + tid] = make_float2(fr, fi);
        sq += fr * fr + fi * fi;
        if (mi == 15) { sr += fr; si += fi; }
    }
    atomicAdd(&ssq[tid], sq);
    if (mi == 15) {
        atomicAdd(&ssr[tid], sr);
        atomicAdd(&ssi[tid], si);
    }
}

// K5: phi synthesis + BN + gate, twiddle-by-rotation. (384,1): lift the VGPR
// cap so g[31]+st[31] (124 regs) stay in registers — R8's bare bound forced
// VGPR=44 and spilled the rotation state to scratch.
__global__ __launch_bounds__(384, 1) void k_synth_final(const float2* __restrict__ G,
                                                        const float* __restrict__ ssr,
                                                        const float* __restrict__ ssi,
                                                        const float* __restrict__ ssq,
                                                        const float* __restrict__ gamma,
                                                        const float* __restrict__ betar,
                                                        const float* __restrict__ betai,
                                                        const float* __restrict__ bias,
                                                        float* __restrict__ out) {
    int bt = blockIdx.x;
    int sd = threadIdx.x, s = sd >> 7;
    float2 g[31], st[31];
#pragma unroll
    for (int mi = 0; mi < 31; ++mi) {
        g[mi] = G[((size_t)bt * 31 + mi) * 384 + sd];
        float sy, sx;
        __sincosf((float)(mi - 15) * (float)(PI_D / 16.0), &sy, &sx);
        st[mi] = make_float2(sx, sy);
    }
    const float invN = 1.0f / 256.0f;
    float mur = 0.f, mui = 0.f;
    if (s == 0) { mur = ssr[sd] * invN; mui = ssi[sd] * invN; }
    float var = ssq[sd] * invN - (mur * mur + mui * mui);
    float scale = gamma[sd] / sqrtf(var + 1e-5f);
    float br = (s == 0) ? betar[sd] : 0.f;
    float bi = (s == 0) ? betai[sd] : 0.f;
    float bb = bias[sd];
    for (int p = 0; p < 32; ++p) {
        float fr = 0.f, fi = 0.f;
#pragma unroll
        for (int mi = 0; mi < 31; ++mi) {
            fr += g[mi].x;
            fi += g[mi].y;
        }
        float yr = (fr - mur) * scale + br;
        float yi = (fi - mui) * scale + bi;
        float mag = sqrtf(yr * yr + yi * yi);
        float f = fmaxf(mag + bb, 0.f) / (mag + 1e-6f);
        out[((size_t)bt * 32 + p) * 384 + sd] = yr * f;
#pragma unroll
        for (int mi = 0; mi < 31; ++mi) {
            float nx = g[mi].x * st[mi].x - g[mi].y * st[mi].y;
            g[mi].y = g[mi].x * st[mi].y + g[mi].y * st[mi].x;
            g[mi].x = nx;
        }
    }
}

extern "C" void kernel_launch(void* const* d_in, const int* in_sizes, int n_in,
                              void* d_out, int out_size, void* d_ws, size_t ws_size,
                              hipStream_t stream) {
    const float* xr    = (const float*)d_in[0];
    const float* xi    = (const float*)d_in[1];
    const float* kr    = (const float*)d_in[2];
    const float* ki    = (const float*)d_in[3];
    const float* gamma = (const float*)d_in[4];
    const float* betar = (const float*)d_in[5];
    const float* betai = (const float*)d_in[6];
    const float* bias  = (const float*)d_in[7];
    float* out = (float*)d_out;

    char* ws = (char*)d_ws;
    float*  A_in   = (float*)(ws + OFF_A_IN);
    float*  A_out  = (float*)(ws + OFF_A_OUT);
    float*  stats  = (float*)(ws + OFF_STATS);
    float*  ssr    = stats;
    float*  ssi    = stats + 384;
    float*  ssq    = stats + 768;
    float2* F      = (float2*)(ws + OFF_R1);  // then oc
    float2* oc     = (float2*)(ws + OFF_R1);
    float2* coeffs = (float2*)(ws + OFF_R2);  // then G
    float2* G      = (float2*)(ws + OFF_R2);

    k_tables<<<229, 256, 0, stream>>>(A_in, A_out, stats);
    k_phi_in<<<512, 512, 0, stream>>>(xr, xi, F);
    k_theta_in<<<dim3(31, 8), 512, 0, stream>>>(F, A_in, coeffs);
    k_mix<<<dim3(256, 2), 384, 0, stream>>>(coeffs, kr, ki, oc);
    k_theta_out<<<dim3(31, 8), 384, 0, stream>>>(oc, A_out, G, ssr, ssi, ssq);
    k_synth_final<<<256, 384, 0, stream>>>(G, ssr, ssi, ssq,
                                           gamma, betar, betai, bias, out);
}

// Round 10
// 194.659 us; speedup vs baseline: 1.3431x; 1.3431x over previous
//
#include <hip/hip_runtime.h>
#include <math.h>

// SpinSphericalBlock: separable spin-weighted SHT -> channel mix -> inverse SHT
// -> complex BN (spin0 mean, via Parseval on G) -> magnitude-ReLU gating.
//
// Constants: B=8, RES=64, RES_OUT=32, L=15, SPINS_IN=(0,1), SPINS_OUT=(0,1,2),
// C_IN=64, C_OUT=128, NM=31. Output: out_size=3,145,728 float32 = Re(y),
// (b,t,p,s,d) row-major (established R0-R4).
//
// R10 (post-mortem R9): k_mix was latency-bound with VGPR_Count=24 -> only ~2
// loads in flight. v3: manual 4-deep double-buffered load pipeline, float2
// kernel loads, launch_bounds(384,3) to lift the VGPR cap. Radix-2 folding in
// both phi-DFTs ((-1)^m identity for p+32 / p+16) cuts VALU ~1.6x.
//
//   K0 k_tables:     Wigner tables (fp64) + zero stats accumulators
//   K1 k_phi_in:     F[bt,m,iu]    = sum_p x[bt,p,iu] e^{-im phi_p}   (radix-2)
//   K2 k_theta_in:   coeffs[b,k,iu]= sum_t A_in[i,k,t] F[b,t,m(k),iu]
//   K3 k_mix:        oc[b,k,sd]    = sum_iu coeffs * kernel[l(k),i,s,u,d]
//   K4 k_theta_out:  G[bt,m,sd]    = sum_l A_out[s,k,t] oc[b,k,sd]  + stats
//   K5 k_synth_final: y = BN(sum_m G e^{+im phi'_p}) -> gate -> Re(y) (radix-2)

#define PI_D 3.14159265358979323846

// ---------------- workspace layout (bytes) ----------------
#define OFF_A_IN    ((size_t)24320)     // 2*256*64 float    = 131072
#define OFF_A_OUT   ((size_t)155648)    // 3*256*32 float    = 98304
#define OFF_STATS   ((size_t)254208)    // 3*384 float       = 4608
#define OFF_R1      ((size_t)260608)    // F (16.25MB) then oc (6.3MB)
#define OFF_R2      ((size_t)25426688)  // coeffs (2.1MB) then G (24.4MB)

__device__ inline int isqrt_k(int k) {
    int l = (int)sqrtf((float)k + 0.5f);
    while (l * l > k) --l;
    while ((l + 1) * (l + 1) <= k) ++l;
    return l;
}

// d^l_{m,n}(theta), exact factorial-sum formula, double precision.
__device__ double wigner_d_dev(int l, int m, int n, double theta, const double* lf) {
    int an = n < 0 ? -n : n;
    int am = m < 0 ? -m : m;
    if (l < an || l < am) return 0.0;
    double cb = cos(0.5 * theta), sb = sin(0.5 * theta);
    double pref = 0.5 * (lf[l + m] + lf[l - m] + lf[l + n] + lf[l - n]);
    int kmin = max(0, n - m), kmax = min(l + n, l - m);
    if (kmax < kmin) return 0.0;
    double p = pow(cb, (double)(2 * l + n - m - 2 * kmin)) * pow(sb, (double)(m - n + 2 * kmin));
    double r = (sb * sb) / (cb * cb);
    double acc = 0.0;
    for (int k = kmin; k <= kmax; ++k) {
        double lg = pref - (lf[l + n - k] + lf[k] + lf[m - n + k] + lf[l - m - k]);
        double term = exp(lg) * p;
        acc += ((m - n + k) & 1) ? -term : term;
        p *= r;
    }
    return acc;
}

// K0: Wigner tables + zero stats. ranges: A_in 32768 | A_out 24576 | stats 1152
__global__ __launch_bounds__(256) void k_tables(float* __restrict__ A_in,
                                                float* __restrict__ A_out,
                                                float* __restrict__ stats) {
    __shared__ double lf[40];
    if (threadIdx.x == 0) {
        lf[0] = 0.0;
        for (int j = 1; j < 40; ++j) lf[j] = lf[j - 1] + log((double)j);
    }
    __syncthreads();
    int idx = blockIdx.x * 256 + threadIdx.x;
    if (idx < 32768) {
        int t = idx & 63, k = (idx >> 6) & 255, i = idx >> 14;
        int l = isqrt_k(k);
        int m = k - l * l - l;
        int n = -i;
        double theta = ((double)t + 0.5) * PI_D / 64.0;
        double w = sin(theta) * (PI_D / 64.0) * (2.0 * PI_D / 64.0);
        double norm = sqrt((2.0 * l + 1.0) / (4.0 * PI_D));
        double d = wigner_d_dev(l, m, n, theta, lf);
        A_in[idx] = (float)(((m & 1) ? -1.0 : 1.0) * norm * w * d);
        return;
    }
    idx -= 32768;
    if (idx < 24576) {
        int t = idx & 31, k = (idx >> 5) & 255, s = idx >> 13;
        int l = isqrt_k(k);
        int m = k - l * l - l;
        int n = -s;
        double theta = ((double)t + 0.5) * PI_D / 32.0;
        double norm = sqrt((2.0 * l + 1.0) / (4.0 * PI_D));
        double d = wigner_d_dev(l, m, n, theta, lf);
        A_out[idx] = (float)(((m & 1) ? -1.0 : 1.0) * norm * d);
        return;
    }
    idx -= 24576;
    if (idx < 1152) stats[idx] = 0.f;
}

// K1: partial phi-DFT, radix-2 folded: x_p and x_{p+32} combine with (-1)^m.
// m = mi0+j-15; j even -> m odd (diff), j odd -> m even (sum). 32 iterations,
// same rotation step e^{-im*2pi/64}. grid 512 (bt), 512 threads.
__global__ __launch_bounds__(512, 2) void k_phi_in(const float* __restrict__ xr,
                                                   const float* __restrict__ xi,
                                                   float2* __restrict__ F) {
    int bt = blockIdx.x;
    int iu = threadIdx.x & 127, mh = threadIdx.x >> 7;
    int mi0 = mh * 8;
    float2 acc[8], w[8], st[8];
#pragma unroll
    for (int j = 0; j < 8; ++j) {
        int m = mi0 + j - 15;
        float sy, sx;
        __sincosf(-(float)m * (float)(PI_D / 32.0), &sy, &sx);
        st[j] = make_float2(sx, sy);
        w[j] = make_float2(1.f, 0.f);
        acc[j] = make_float2(0.f, 0.f);
    }
    const float* xrb = xr + (size_t)bt * 8192 + iu;
    const float* xib = xi + (size_t)bt * 8192 + iu;
    for (int p = 0; p < 32; ++p) {
        float a  = xrb[(size_t)p * 128];
        float b  = xib[(size_t)p * 128];
        float a2 = xrb[(size_t)(p + 32) * 128];
        float b2 = xib[(size_t)(p + 32) * 128];
        float sar = a + a2, sai = b + b2;   // for even m
        float dar = a - a2, dai = b - b2;   // for odd m
#pragma unroll
        for (int j = 0; j < 8; ++j) {
            float ur = (j & 1) ? sar : dar;  // j odd -> m even
            float ui = (j & 1) ? sai : dai;
            acc[j].x += ur * w[j].x - ui * w[j].y;
            acc[j].y += ur * w[j].y + ui * w[j].x;
            float nx = w[j].x * st[j].x - w[j].y * st[j].y;
            w[j].y = w[j].x * st[j].y + w[j].y * st[j].x;
            w[j].x = nx;
        }
    }
    float2* Fb = F + (size_t)bt * 31 * 128 + iu;
#pragma unroll
    for (int j = 0; j < 8; ++j) {
        int mi = mi0 + j;
        if (mi < 31) Fb[(size_t)mi * 128] = acc[j];
    }
}

// K2: theta contraction. grid (31, 8) = (mi, b), 512 threads (iu, th=t-quarter).
__global__ __launch_bounds__(512, 2) void k_theta_in(const float2* __restrict__ F,
                                                     const float* __restrict__ A_in,
                                                     float2* __restrict__ coeffs) {
    __shared__ float A[2][16][64];      // 8 KB, zero-padded below |m|
    __shared__ float2 red[2][16][128];  // 32 KB reduction buffer
    int mi = blockIdx.x, b = blockIdx.y;
    int m = mi - 15;
    int am = m < 0 ? -m : m;
    int tid = threadIdx.x;
    for (int idx = tid; idx < 2048; idx += 512) {
        int i = idx >> 10, j = (idx >> 6) & 15, t = idx & 63;
        float v = 0.f;
        if (j >= am) v = A_in[((size_t)i * 256 + (j * j + j + m)) * 64 + t];
        A[i][j][t] = v;
    }
    __syncthreads();
    int iu = tid & 127, th = tid >> 7, i = iu >> 6;
    float2 acc[16];
#pragma unroll
    for (int j = 0; j < 16; ++j) acc[j] = make_float2(0.f, 0.f);
    const float2* Fb = F + ((size_t)b * 64 * 31 + mi) * 128 + iu;
    for (int tt = 0; tt < 16; ++tt) {
        int t = th * 16 + tt;
        float2 f = Fb[(size_t)t * 31 * 128];
#pragma unroll
        for (int j = 0; j < 16; ++j) {
            float a = A[i][j][t];
            acc[j].x += a * f.x;
            acc[j].y += a * f.y;
        }
    }
    if (th >= 2) {
#pragma unroll
        for (int j = 0; j < 16; ++j) red[th - 2][j][iu] = acc[j];
    }
    __syncthreads();
    if (th < 2) {
#pragma unroll
        for (int j = 0; j < 16; ++j) {
            float2 r = red[th][j][iu];
            acc[j].x += r.x;
            acc[j].y += r.y;
        }
    }
    __syncthreads();
    if (th == 1) {
#pragma unroll
        for (int j = 0; j < 16; ++j) red[0][j][iu] = acc[j];
    }
    __syncthreads();
    if (th == 0) {
#pragma unroll
        for (int j = 0; j < 16; ++j) {
            if (j >= am) {
                float2 r = red[0][j][iu];
                coeffs[((size_t)b * 256 + (j * j + j + m)) * 128 + iu] =
                    make_float2(acc[j].x + r.x, acc[j].y + r.y);
            }
        }
    }
}

// K3: channel mix v3. grid (128 kpair, 4 bq), 384 threads = (kk 2)x(s 3)x(dp 64).
// Thread: 2 sd (float2 kernel loads) x 2 b. Manual 4-deep double-buffered
// kernel-load pipeline (R9 post-mortem: compiler at VGPR=24 kept only ~2 loads
// in flight -> 70us latency-bound). launch_bounds(384,3): VGPR cap ~170.
__global__ __launch_bounds__(384, 3) void k_mix(const float2* __restrict__ coeffs,
                                                const float* __restrict__ kr,
                                                const float* __restrict__ ki,
                                                float2* __restrict__ oc) {
    __shared__ float2 cs[2][2][128];  // [kk][bb][iu], 4 KB
    int k0 = blockIdx.x * 2;
    int b0 = blockIdx.y * 2;
    int tid = threadIdx.x;
    for (int idx = tid; idx < 512; idx += 384) {
        int kk = idx >> 8, bb = (idx >> 7) & 1, iu = idx & 127;
        cs[kk][bb][iu] = coeffs[((size_t)(b0 + bb) * 256 + (k0 + kk)) * 128 + iu];
    }
    __syncthreads();
    int kk = tid / 192, r = tid % 192;
    int s = r >> 6, dp = r & 63;
    int k = k0 + kk;
    int l = isqrt_k(k);
    float2 acc[2][2];  // [bb][which-d]
#pragma unroll
    for (int bb = 0; bb < 2; ++bb) {
        acc[bb][0] = make_float2(0.f, 0.f);
        acc[bb][1] = make_float2(0.f, 0.f);
    }
    for (int i = 0; i < 2; ++i) {
        const float2* krp = (const float2*)(kr + (size_t)(6 * l + 3 * i + s) * 8192) + dp;
        const float2* kip = (const float2*)(ki + (size_t)(6 * l + 3 * i + s) * 8192) + dp;
        float2 w0[4], w1[4];
#pragma unroll
        for (int j = 0; j < 4; ++j) { w0[j] = krp[(size_t)j * 64]; w1[j] = kip[(size_t)j * 64]; }
        for (int ub = 0; ub < 64; ub += 4) {
            float2 n0[4], n1[4];
            if (ub + 4 < 64) {
#pragma unroll
                for (int j = 0; j < 4; ++j) {
                    n0[j] = krp[(size_t)(ub + 4 + j) * 64];
                    n1[j] = kip[(size_t)(ub + 4 + j) * 64];
                }
            }
#pragma unroll
            for (int j = 0; j < 4; ++j) {
                int iu = i * 64 + ub + j;
                float2 wr = w0[j], wi = w1[j];
#pragma unroll
                for (int bb = 0; bb < 2; ++bb) {
                    float2 cv = cs[kk][bb][iu];
                    acc[bb][0].x += cv.x * wr.x - cv.y * wi.x;
                    acc[bb][0].y += cv.x * wi.x + cv.y * wr.x;
                    acc[bb][1].x += cv.x * wr.y - cv.y * wi.y;
                    acc[bb][1].y += cv.x * wi.y + cv.y * wr.y;
                }
            }
#pragma unroll
            for (int j = 0; j < 4; ++j) { w0[j] = n0[j]; w1[j] = n1[j]; }
        }
    }
#pragma unroll
    for (int bb = 0; bb < 2; ++bb) {
        float4 stv = make_float4(acc[bb][0].x, acc[bb][0].y, acc[bb][1].x, acc[bb][1].y);
        *(float4*)&oc[((size_t)(b0 + bb) * 256 + k) * 384 + s * 128 + 2 * dp] = stv;
    }
}

// K4: theta expansion + stats. grid (31, 8), 384 threads.
__global__ __launch_bounds__(384, 2) void k_theta_out(const float2* __restrict__ oc,
                                                      const float* __restrict__ A_out,
                                                      float2* __restrict__ G,
                                                      float* __restrict__ ssr,
                                                      float* __restrict__ ssi,
                                                      float* __restrict__ ssq) {
    __shared__ float Ao[3][16][32];  // 6KB
    int mi = blockIdx.x, b = blockIdx.y;
    int m = mi - 15;
    int am = m < 0 ? -m : m;
    int tid = threadIdx.x;
    for (int idx = tid; idx < 1536; idx += 384) {
        int s = idx >> 9, j = (idx >> 5) & 15, t = idx & 31;
        float v = 0.f;
        if (j >= am) v = A_out[((size_t)s * 256 + (j * j + j + m)) * 32 + t];
        Ao[s][j][t] = v;
    }
    __syncthreads();
    int s = tid >> 7;
    float2 c[16];
#pragma unroll
    for (int j = 0; j < 16; ++j) {
        c[j] = make_float2(0.f, 0.f);
        if (j >= am) c[j] = oc[((size_t)b * 256 + (j * j + j + m)) * 384 + tid];
    }
    float sq = 0.f, sr = 0.f, si = 0.f;
    for (int t = 0; t < 32; ++t) {
        float fr = 0.f, fi = 0.f;
#pragma unroll
        for (int j = 0; j < 16; ++j) {
            float a = Ao[s][j][t];
            fr += a * c[j].x;
            fi += a * c[j].y;
        }
        G[(((size_t)b * 32 + t) * 31 + mi) * 384 + tid] = make_float2(fr, fi);
        sq += fr * fr + fi * fi;
        if (mi == 15) { sr += fr; si += fi; }
    }
    atomicAdd(&ssq[tid], sq);
    if (mi == 15) {
        atomicAdd(&ssr[tid], sr);
        atomicAdd(&ssi[tid], si);
    }
}

// K5: phi synthesis + BN + gate, radix-2 folded: p and p+16 share one rotation
// state via e^{im*pi} = (-1)^m (mi odd -> m even -> +). 16 iterations.
__global__ __launch_bounds__(384, 1) void k_synth_final(const float2* __restrict__ G,
                                                        const float* __restrict__ ssr,
                                                        const float* __restrict__ ssi,
                                                        const float* __restrict__ ssq,
                                                        const float* __restrict__ gamma,
                                                        const float* __restrict__ betar,
                                                        const float* __restrict__ betai,
                                                        const float* __restrict__ bias,
                                                        float* __restrict__ out) {
    int bt = blockIdx.x;
    int sd = threadIdx.x, s = sd >> 7;
    float2 g[31], st[31];
#pragma unroll
    for (int mi = 0; mi < 31; ++mi) {
        g[mi] = G[((size_t)bt * 31 + mi) * 384 + sd];
        float sy, sx;
        __sincosf((float)(mi - 15) * (float)(PI_D / 16.0), &sy, &sx);
        st[mi] = make_float2(sx, sy);
    }
    const float invN = 1.0f / 256.0f;
    float mur = 0.f, mui = 0.f;
    if (s == 0) { mur = ssr[sd] * invN; mui = ssi[sd] * invN; }
    float var = ssq[sd] * invN - (mur * mur + mui * mui);
    float scale = gamma[sd] / sqrtf(var + 1e-5f);
    float br = (s == 0) ? betar[sd] : 0.f;
    float bi = (s == 0) ? betai[sd] : 0.f;
    float bb = bias[sd];
    float* ob = out + (size_t)bt * 32 * 384 + sd;
    for (int p = 0; p < 16; ++p) {
        float fr = 0.f, fi = 0.f, fr2 = 0.f, fi2 = 0.f;
#pragma unroll
        for (int mi = 0; mi < 31; ++mi) {
            fr += g[mi].x;
            fi += g[mi].y;
            if (mi & 1) { fr2 += g[mi].x; fi2 += g[mi].y; }  // m even
            else        { fr2 -= g[mi].x; fi2 -= g[mi].y; }  // m odd
        }
        {
            float yr = (fr - mur) * scale + br;
            float yi = (fi - mui) * scale + bi;
            float mag = sqrtf(yr * yr + yi * yi);
            float f = fmaxf(mag + bb, 0.f) / (mag + 1e-6f);
            ob[(size_t)p * 384] = yr * f;
        }
        {
            float yr = (fr2 - mur) * scale + br;
            float yi = (fi2 - mui) * scale + bi;
            float mag = sqrtf(yr * yr + yi * yi);
            float f = fmaxf(mag + bb, 0.f) / (mag + 1e-6f);
            ob[(size_t)(p + 16) * 384] = yr * f;
        }
#pragma unroll
        for (int mi = 0; mi < 31; ++mi) {
            float nx = g[mi].x * st[mi].x - g[mi].y * st[mi].y;
            g[mi].y = g[mi].x * st[mi].y + g[mi].y * st[mi].x;
            g[mi].x = nx;
        }
    }
}

extern "C" void kernel_launch(void* const* d_in, const int* in_sizes, int n_in,
                              void* d_out, int out_size, void* d_ws, size_t ws_size,
                              hipStream_t stream) {
    const float* xr    = (const float*)d_in[0];
    const float* xi    = (const float*)d_in[1];
    const float* kr    = (const float*)d_in[2];
    const float* ki    = (const float*)d_in[3];
    const float* gamma = (const float*)d_in[4];
    const float* betar = (const float*)d_in[5];
    const float* betai = (const float*)d_in[6];
    const float* bias  = (const float*)d_in[7];
    float* out = (float*)d_out;

    char* ws = (char*)d_ws;
    float*  A_in   = (float*)(ws + OFF_A_IN);
    float*  A_out  = (float*)(ws + OFF_A_OUT);
    float*  stats  = (float*)(ws + OFF_STATS);
    float*  ssr    = stats;
    float*  ssi    = stats + 384;
    float*  ssq    = stats + 768;
    float2* F      = (float2*)(ws + OFF_R1);  // then oc
    float2* oc     = (float2*)(ws + OFF_R1);
    float2* coeffs = (float2*)(ws + OFF_R2);  // then G
    float2* G      = (float2*)(ws + OFF_R2);

    k_tables<<<229, 256, 0, stream>>>(A_in, A_out, stats);
    k_phi_in<<<512, 512, 0, stream>>>(xr, xi, F);
    k_theta_in<<<dim3(31, 8), 512, 0, stream>>>(F, A_in, coeffs);
    k_mix<<<dim3(128, 4), 384, 0, stream>>>(coeffs, kr, ki, oc);
    k_theta_out<<<dim3(31, 8), 384, 0, stream>>>(oc, A_out, G, ssr, ssi, ssq);
    k_synth_final<<<256, 384, 0, stream>>>(G, ssr, ssi, ssq,
                                           gamma, betar, betai, bias, out);
}

// Round 11
// 184.361 us; speedup vs baseline: 1.4181x; 1.0559x over previous
//
#include <hip/hip_runtime.h>
#include <math.h>

// SpinSphericalBlock: separable spin-weighted SHT -> channel mix -> inverse SHT
// -> complex BN (spin0 mean, via Parseval on G) -> magnitude-ReLU gating.
//
// Constants: B=8, RES=64, RES_OUT=32, L=15, SPINS_IN=(0,1), SPINS_OUT=(0,1,2),
// C_IN=64, C_OUT=128, NM=31. Output: out_size=3,145,728 float32 = Re(y),
// (b,t,p,s,d) row-major (established R0-R4).
//
// R11 (post-mortem R10): all kernels now < 41us (fill-reset dominated the
// profile). Model says k_tables was the big serial sink: up to 16 fp64 exp +
// 2 fp64 pow per element + a serial 40-log loop behind a barrier. Fix:
// constant lgamma table + exact ratio-recurrence (3 transcendentals/element),
// and fold table gen into k_phi_in's grid (blocks >= 512) so it overlaps.
//
//   K1 k_phi_tables: blocks<512: F[bt,m,iu] = sum_p x e^{-im phi_p} (radix-2)
//                    blocks>=512: Wigner tables (fp64 recurrence) + zero stats
//   K2 k_theta_in:   coeffs[b,k,iu]= sum_t A_in[i,k,t] F[b,t,m(k),iu]
//   K3 k_mix:        oc[b,k,sd]    = sum_iu coeffs * kernel[l(k),i,s,u,d]
//   K4 k_theta_out:  G[bt,m,sd]    = sum_l A_out[s,k,t] oc[b,k,sd]  + stats
//   K5 k_synth_final: y = BN(sum_m G e^{+im phi'_p}) -> gate -> Re(y) (radix-2)

#define PI_D 3.14159265358979323846

// ---------------- workspace layout (bytes) ----------------
#define OFF_A_IN    ((size_t)24320)     // 2*256*64 float    = 131072
#define OFF_A_OUT   ((size_t)155648)    // 3*256*32 float    = 98304
#define OFF_STATS   ((size_t)254208)    // 3*384 float       = 4608
#define OFF_R1      ((size_t)260608)    // F (16.25MB) then oc (6.3MB)
#define OFF_R2      ((size_t)25426688)  // coeffs (2.1MB) then G (24.4MB)

// ln(j!) for j=0..30 (exact constants; max index used is l+m = 30)
__constant__ double LF[31] = {
    0.0, 0.0, 0.6931471805599453, 1.791759469228055, 3.1780538303479458,
    4.787491742782046, 6.579251212010101, 8.525161361065415,
    10.604602902745251, 12.801827480081469, 15.104412573075516,
    17.502307845873887, 19.987214495661885, 22.552163853123425,
    25.19122118273868, 27.89927138384089, 30.671860106080672,
    33.50507345013689, 36.39544520803305, 39.339884187199495,
    42.335616460753485, 45.38013889847691, 48.47118135183523,
    51.60667556776438, 54.78472939811232, 58.00360522298052,
    61.261701761002, 64.55753862700634, 67.88974313718154,
    71.25703896716801, 74.65823634883016};

__device__ inline int isqrt_k(int k) {
    int l = (int)sqrtf((float)k + 0.5f);
    while (l * l > k) --l;
    while ((l + 1) * (l + 1) <= k) ++l;
    return l;
}

// d^l_{m,n}(theta) via seed term (1 exp + 2 log) + exact ratio recurrence.
__device__ double wigner_d_rec(int l, int m, int n, double theta) {
    int an = n < 0 ? -n : n;
    int am = m < 0 ? -m : m;
    if (l < an || l < am) return 0.0;
    int kmin = max(0, n - m), kmax = min(l + n, l - m);
    if (kmax < kmin) return 0.0;
    double cb = cos(0.5 * theta), sb = sin(0.5 * theta);
    double pref = 0.5 * (LF[l + m] + LF[l - m] + LF[l + n] + LF[l - n]);
    double lterm = pref
        - (LF[l + n - kmin] + LF[kmin] + LF[m - n + kmin] + LF[l - m - kmin])
        + (double)(2 * l + n - m - 2 * kmin) * log(cb)
        + (double)(m - n + 2 * kmin) * log(sb);
    double term = exp(lterm);
    if ((m - n + kmin) & 1) term = -term;
    double r = (sb * sb) / (cb * cb);
    double acc = term;
    for (int k = kmin; k < kmax; ++k) {
        term *= -((double)((l + n - k) * (l - m - k)) * r)
                / ((double)((k + 1) * (m - n + k + 1)));
        acc += term;
    }
    return acc;
}

// K1: fused phi-DFT (blocks 0..511) + table generation (blocks 512..626).
// phi: radix-2 folded rotation DFT (R10). tables: recurrence Wigner (above).
__global__ __launch_bounds__(512, 2) void k_phi_tables(const float* __restrict__ xr,
                                                       const float* __restrict__ xi,
                                                       float2* __restrict__ F,
                                                       float* __restrict__ A_in,
                                                       float* __restrict__ A_out,
                                                       float* __restrict__ stats) {
    if (blockIdx.x >= 512) {
        // ---- table path: A_in 32768 | A_out 24576 | stats 1152 ----
        int idx = (blockIdx.x - 512) * 512 + threadIdx.x;
        if (idx < 32768) {  // A_in[i][k][t] = (-1)^m norm_l w_t d^l_{m,-i}(th_t)
            int t = idx & 63, k = (idx >> 6) & 255, i = idx >> 14;
            int l = isqrt_k(k);
            int m = k - l * l - l;
            double theta = ((double)t + 0.5) * PI_D / 64.0;
            double w = sin(theta) * (PI_D / 64.0) * (2.0 * PI_D / 64.0);
            double norm = sqrt((2.0 * l + 1.0) / (4.0 * PI_D));
            double d = wigner_d_rec(l, m, -i, theta);
            A_in[idx] = (float)(((m & 1) ? -1.0 : 1.0) * norm * w * d);
            return;
        }
        idx -= 32768;
        if (idx < 24576) {  // A_out[s][k][t] = (-1)^m norm_l d^l_{m,-s}(th'_t)
            int t = idx & 31, k = (idx >> 5) & 255, s = idx >> 13;
            int l = isqrt_k(k);
            int m = k - l * l - l;
            double theta = ((double)t + 0.5) * PI_D / 32.0;
            double norm = sqrt((2.0 * l + 1.0) / (4.0 * PI_D));
            double d = wigner_d_rec(l, m, -s, theta);
            A_out[idx] = (float)(((m & 1) ? -1.0 : 1.0) * norm * d);
            return;
        }
        idx -= 24576;
        if (idx < 1152) stats[idx] = 0.f;  // ssr[384] | ssi[384] | ssq[384]
        return;
    }
    // ---- phi path: radix-2 folded x_p/x_{p+32} with (-1)^m ----
    int bt = blockIdx.x;
    int iu = threadIdx.x & 127, mh = threadIdx.x >> 7;
    int mi0 = mh * 8;
    float2 acc[8], w[8], st[8];
#pragma unroll
    for (int j = 0; j < 8; ++j) {
        int m = mi0 + j - 15;
        float sy, sx;
        __sincosf(-(float)m * (float)(PI_D / 32.0), &sy, &sx);
        st[j] = make_float2(sx, sy);
        w[j] = make_float2(1.f, 0.f);
        acc[j] = make_float2(0.f, 0.f);
    }
    const float* xrb = xr + (size_t)bt * 8192 + iu;
    const float* xib = xi + (size_t)bt * 8192 + iu;
    for (int p = 0; p < 32; ++p) {
        float a  = xrb[(size_t)p * 128];
        float b  = xib[(size_t)p * 128];
        float a2 = xrb[(size_t)(p + 32) * 128];
        float b2 = xib[(size_t)(p + 32) * 128];
        float sar = a + a2, sai = b + b2;   // for even m
        float dar = a - a2, dai = b - b2;   // for odd m
#pragma unroll
        for (int j = 0; j < 8; ++j) {
            float ur = (j & 1) ? sar : dar;  // j odd -> m even
            float ui = (j & 1) ? sai : dai;
            acc[j].x += ur * w[j].x - ui * w[j].y;
            acc[j].y += ur * w[j].y + ui * w[j].x;
            float nx = w[j].x * st[j].x - w[j].y * st[j].y;
            w[j].y = w[j].x * st[j].y + w[j].y * st[j].x;
            w[j].x = nx;
        }
    }
    float2* Fb = F + (size_t)bt * 31 * 128 + iu;
#pragma unroll
    for (int j = 0; j < 8; ++j) {
        int mi = mi0 + j;
        if (mi < 31) Fb[(size_t)mi * 128] = acc[j];
    }
}

// K2: theta contraction. grid (31, 8) = (mi, b), 512 threads (iu, th=t-quarter).
__global__ __launch_bounds__(512, 2) void k_theta_in(const float2* __restrict__ F,
                                                     const float* __restrict__ A_in,
                                                     float2* __restrict__ coeffs) {
    __shared__ float A[2][16][64];      // 8 KB, zero-padded below |m|
    __shared__ float2 red[2][16][128];  // 32 KB reduction buffer
    int mi = blockIdx.x, b = blockIdx.y;
    int m = mi - 15;
    int am = m < 0 ? -m : m;
    int tid = threadIdx.x;
    for (int idx = tid; idx < 2048; idx += 512) {
        int i = idx >> 10, j = (idx >> 6) & 15, t = idx & 63;
        float v = 0.f;
        if (j >= am) v = A_in[((size_t)i * 256 + (j * j + j + m)) * 64 + t];
        A[i][j][t] = v;
    }
    __syncthreads();
    int iu = tid & 127, th = tid >> 7, i = iu >> 6;
    float2 acc[16];
#pragma unroll
    for (int j = 0; j < 16; ++j) acc[j] = make_float2(0.f, 0.f);
    const float2* Fb = F + ((size_t)b * 64 * 31 + mi) * 128 + iu;
    for (int tt = 0; tt < 16; ++tt) {
        int t = th * 16 + tt;
        float2 f = Fb[(size_t)t * 31 * 128];
#pragma unroll
        for (int j = 0; j < 16; ++j) {
            float a = A[i][j][t];
            acc[j].x += a * f.x;
            acc[j].y += a * f.y;
        }
    }
    if (th >= 2) {
#pragma unroll
        for (int j = 0; j < 16; ++j) red[th - 2][j][iu] = acc[j];
    }
    __syncthreads();
    if (th < 2) {
#pragma unroll
        for (int j = 0; j < 16; ++j) {
            float2 r = red[th][j][iu];
            acc[j].x += r.x;
            acc[j].y += r.y;
        }
    }
    __syncthreads();
    if (th == 1) {
#pragma unroll
        for (int j = 0; j < 16; ++j) red[0][j][iu] = acc[j];
    }
    __syncthreads();
    if (th == 0) {
#pragma unroll
        for (int j = 0; j < 16; ++j) {
            if (j >= am) {
                float2 r = red[0][j][iu];
                coeffs[((size_t)b * 256 + (j * j + j + m)) * 128 + iu] =
                    make_float2(acc[j].x + r.x, acc[j].y + r.y);
            }
        }
    }
}

// K3: channel mix v3 (unchanged from R10). grid (128, 4), 384 threads.
__global__ __launch_bounds__(384, 3) void k_mix(const float2* __restrict__ coeffs,
                                                const float* __restrict__ kr,
                                                const float* __restrict__ ki,
                                                float2* __restrict__ oc) {
    __shared__ float2 cs[2][2][128];  // [kk][bb][iu], 4 KB
    int k0 = blockIdx.x * 2;
    int b0 = blockIdx.y * 2;
    int tid = threadIdx.x;
    for (int idx = tid; idx < 512; idx += 384) {
        int kk = idx >> 8, bb = (idx >> 7) & 1, iu = idx & 127;
        cs[kk][bb][iu] = coeffs[((size_t)(b0 + bb) * 256 + (k0 + kk)) * 128 + iu];
    }
    __syncthreads();
    int kk = tid / 192, r = tid % 192;
    int s = r >> 6, dp = r & 63;
    int k = k0 + kk;
    int l = isqrt_k(k);
    float2 acc[2][2];
#pragma unroll
    for (int bb = 0; bb < 2; ++bb) {
        acc[bb][0] = make_float2(0.f, 0.f);
        acc[bb][1] = make_float2(0.f, 0.f);
    }
    for (int i = 0; i < 2; ++i) {
        const float2* krp = (const float2*)(kr + (size_t)(6 * l + 3 * i + s) * 8192) + dp;
        const float2* kip = (const float2*)(ki + (size_t)(6 * l + 3 * i + s) * 8192) + dp;
        float2 w0[4], w1[4];
#pragma unroll
        for (int j = 0; j < 4; ++j) { w0[j] = krp[(size_t)j * 64]; w1[j] = kip[(size_t)j * 64]; }
        for (int ub = 0; ub < 64; ub += 4) {
            float2 n0[4], n1[4];
            if (ub + 4 < 64) {
#pragma unroll
                for (int j = 0; j < 4; ++j) {
                    n0[j] = krp[(size_t)(ub + 4 + j) * 64];
                    n1[j] = kip[(size_t)(ub + 4 + j) * 64];
                }
            }
#pragma unroll
            for (int j = 0; j < 4; ++j) {
                int iu = i * 64 + ub + j;
                float2 wr = w0[j], wi = w1[j];
#pragma unroll
                for (int bb = 0; bb < 2; ++bb) {
                    float2 cv = cs[kk][bb][iu];
                    acc[bb][0].x += cv.x * wr.x - cv.y * wi.x;
                    acc[bb][0].y += cv.x * wi.x + cv.y * wr.x;
                    acc[bb][1].x += cv.x * wr.y - cv.y * wi.y;
                    acc[bb][1].y += cv.x * wi.y + cv.y * wr.y;
                }
            }
#pragma unroll
            for (int j = 0; j < 4; ++j) { w0[j] = n0[j]; w1[j] = n1[j]; }
        }
    }
#pragma unroll
    for (int bb = 0; bb < 2; ++bb) {
        float4 stv = make_float4(acc[bb][0].x, acc[bb][0].y, acc[bb][1].x, acc[bb][1].y);
        *(float4*)&oc[((size_t)(b0 + bb) * 256 + k) * 384 + s * 128 + 2 * dp] = stv;
    }
}

// K4: theta expansion + stats (unchanged). grid (31, 8), 384 threads.
__global__ __launch_bounds__(384, 2) void k_theta_out(const float2* __restrict__ oc,
                                                      const float* __restrict__ A_out,
                                                      float2* __restrict__ G,
                                                      float* __restrict__ ssr,
                                                      float* __restrict__ ssi,
                                                      float* __restrict__ ssq) {
    __shared__ float Ao[3][16][32];  // 6KB
    int mi = blockIdx.x, b = blockIdx.y;
    int m = mi - 15;
    int am = m < 0 ? -m : m;
    int tid = threadIdx.x;
    for (int idx = tid; idx < 1536; idx += 384) {
        int s = idx >> 9, j = (idx >> 5) & 15, t = idx & 31;
        float v = 0.f;
        if (j >= am) v = A_out[((size_t)s * 256 + (j * j + j + m)) * 32 + t];
        Ao[s][j][t] = v;
    }
    __syncthreads();
    int s = tid >> 7;
    float2 c[16];
#pragma unroll
    for (int j = 0; j < 16; ++j) {
        c[j] = make_float2(0.f, 0.f);
        if (j >= am) c[j] = oc[((size_t)b * 256 + (j * j + j + m)) * 384 + tid];
    }
    float sq = 0.f, sr = 0.f, si = 0.f;
    for (int t = 0; t < 32; ++t) {
        float fr = 0.f, fi = 0.f;
#pragma unroll
        for (int j = 0; j < 16; ++j) {
            float a = Ao[s][j][t];
            fr += a * c[j].x;
            fi += a * c[j].y;
        }
        G[(((size_t)b * 32 + t) * 31 + mi) * 384 + tid] = make_float2(fr, fi);
        sq += fr * fr + fi * fi;
        if (mi == 15) { sr += fr; si += fi; }
    }
    atomicAdd(&ssq[tid], sq);
    if (mi == 15) {
        atomicAdd(&ssr[tid], sr);
        atomicAdd(&ssi[tid], si);
    }
}

// K5: phi synthesis + BN + gate, radix-2 folded (unchanged). grid 256, 384 thr.
__global__ __launch_bounds__(384, 1) void k_synth_final(const float2* __restrict__ G,
                                                        const float* __restrict__ ssr,
                                                        const float* __restrict__ ssi,
                                                        const float* __restrict__ ssq,
                                                        const float* __restrict__ gamma,
                                                        const float* __restrict__ betar,
                                                        const float* __restrict__ betai,
                                                        const float* __restrict__ bias,
                                                        float* __restrict__ out) {
    int bt = blockIdx.x;
    int sd = threadIdx.x, s = sd >> 7;
    float2 g[31], st[31];
#pragma unroll
    for (int mi = 0; mi < 31; ++mi) {
        g[mi] = G[((size_t)bt * 31 + mi) * 384 + sd];
        float sy, sx;
        __sincosf((float)(mi - 15) * (float)(PI_D / 16.0), &sy, &sx);
        st[mi] = make_float2(sx, sy);
    }
    const float invN = 1.0f / 256.0f;
    float mur = 0.f, mui = 0.f;
    if (s == 0) { mur = ssr[sd] * invN; mui = ssi[sd] * invN; }
    float var = ssq[sd] * invN - (mur * mur + mui * mui);
    float scale = gamma[sd] / sqrtf(var + 1e-5f);
    float br = (s == 0) ? betar[sd] : 0.f;
    float bi = (s == 0) ? betai[sd] : 0.f;
    float bb = bias[sd];
    float* ob = out + (size_t)bt * 32 * 384 + sd;
    for (int p = 0; p < 16; ++p) {
        float fr = 0.f, fi = 0.f, fr2 = 0.f, fi2 = 0.f;
#pragma unroll
        for (int mi = 0; mi < 31; ++mi) {
            fr += g[mi].x;
            fi += g[mi].y;
            if (mi & 1) { fr2 += g[mi].x; fi2 += g[mi].y; }  // m even
            else        { fr2 -= g[mi].x; fi2 -= g[mi].y; }  // m odd
        }
        {
            float yr = (fr - mur) * scale + br;
            float yi = (fi - mui) * scale + bi;
            float mag = sqrtf(yr * yr + yi * yi);
            float f = fmaxf(mag + bb, 0.f) / (mag + 1e-6f);
            ob[(size_t)p * 384] = yr * f;
        }
        {
            float yr = (fr2 - mur) * scale + br;
            float yi = (fi2 - mui) * scale + bi;
            float mag = sqrtf(yr * yr + yi * yi);
            float f = fmaxf(mag + bb, 0.f) / (mag + 1e-6f);
            ob[(size_t)(p + 16) * 384] = yr * f;
        }
#pragma unroll
        for (int mi = 0; mi < 31; ++mi) {
            float nx = g[mi].x * st[mi].x - g[mi].y * st[mi].y;
            g[mi].y = g[mi].x * st[mi].y + g[mi].y * st[mi].x;
            g[mi].x = nx;
        }
    }
}

extern "C" void kernel_launch(void* const* d_in, const int* in_sizes, int n_in,
                              void* d_out, int out_size, void* d_ws, size_t ws_size,
                              hipStream_t stream) {
    const float* xr    = (const float*)d_in[0];
    const float* xi    = (const float*)d_in[1];
    const float* kr    = (const float*)d_in[2];
    const float* ki    = (const float*)d_in[3];
    const float* gamma = (const float*)d_in[4];
    const float* betar = (const float*)d_in[5];
    const float* betai = (const float*)d_in[6];
    const float* bias  = (const float*)d_in[7];
    float* out = (float*)d_out;

    char* ws = (char*)d_ws;
    float*  A_in   = (float*)(ws + OFF_A_IN);
    float*  A_out  = (float*)(ws + OFF_A_OUT);
    float*  stats  = (float*)(ws + OFF_STATS);
    float*  ssr    = stats;
    float*  ssi    = stats + 384;
    float*  ssq    = stats + 768;
    float2* F      = (float2*)(ws + OFF_R1);  // then oc
    float2* oc     = (float2*)(ws + OFF_R1);
    float2* coeffs = (float2*)(ws + OFF_R2);  // then G
    float2* G      = (float2*)(ws + OFF_R2);

    k_phi_tables<<<627, 512, 0, stream>>>(xr, xi, F, A_in, A_out, stats);
    k_theta_in<<<dim3(31, 8), 512, 0, stream>>>(F, A_in, coeffs);
    k_mix<<<dim3(128, 4), 384, 0, stream>>>(coeffs, kr, ki, oc);
    k_theta_out<<<dim3(31, 8), 384, 0, stream>>>(oc, A_out, G, ssr, ssi, ssq);
    k_synth_final<<<256, 384, 0, stream>>>(G, ssr, ssi, ssq,
                                           gamma, betar, betai, bias, out);
}